// Round 1
// baseline (168.687 us; speedup 1.0000x reference)
//
#include <hip/hip_runtime.h>
#include <cstdint>

#define NRAD 4096
#define NLID 16384
#define KMIX 8
#define TOPK 10
#define CF   16
#define LOG2PI 1.8378770664093453f

static constexpr unsigned INF_D2 = 62851u;   // > max real d2 (40^2 + 2*175^2 = 62850)

// ---------------------------------------------------------------- pack lidar
// (b,z,y,x) -> u32: b[2b]<<22 | z[6b]<<16 | y[8b]<<8 | x[8b]
__global__ __launch_bounds__(256) void pack_lidar(const int* __restrict__ lidar_indices,
                                                  unsigned* __restrict__ packed) {
    int i = blockIdx.x * 256 + threadIdx.x;
    int4 li = ((const int4*)lidar_indices)[i];
    packed[i] = ((unsigned)li.x << 22) | ((unsigned)li.y << 16) |
                ((unsigned)li.z << 8)  | (unsigned)li.w;
}

// ---------------------------------------------------------------- top-10 NN
// One wave (64 lanes) per radar row; 4 waves per block.
// Key = (d2<<14)|idx  (same batch)  or  (62851<<14)|idx  (different batch).
// Unsigned-min over keys == lax.top_k(-d2) order incl. tie-break by index.
__global__ __launch_bounds__(256) void topk_kernel(const unsigned* __restrict__ packed,
                                                   const int* __restrict__ radar_indices,
                                                   int* __restrict__ nn_out,
                                                   int* __restrict__ matched_out) {
    int lane = threadIdx.x & 63;
    int row  = blockIdx.x * 4 + (threadIdx.x >> 6);
    int4 ri = ((const int4*)radar_indices)[row];
    int rb = ri.x, rz = ri.y, ry = ri.z, rx = ri.w;

    unsigned t[TOPK];
#pragma unroll
    for (int i = 0; i < TOPK; ++i) t[i] = 0xFFFFFFFFu;

    for (int it = 0; it < NLID / 256; ++it) {
        uint4 p4 = ((const uint4*)packed)[it * 64 + lane];
        unsigned base = it * 256 + lane * 4;
        unsigned ps[4] = {p4.x, p4.y, p4.z, p4.w};
#pragma unroll
        for (int j = 0; j < 4; ++j) {
            unsigned p = ps[j];
            int b  = (int)(p >> 22);
            int dz = (int)((p >> 16) & 63u)  - rz;
            int dy = (int)((p >> 8)  & 255u) - ry;
            int dx = (int)(p & 255u)         - rx;
            unsigned d2 = (unsigned)(dz * dz + dy * dy + dx * dx);
            unsigned hi = (b == rb) ? d2 : INF_D2;
            unsigned key = (hi << 14) | (base + j);
            if (key < t[TOPK - 1]) {          // insert (keeps t ascending)
                t[TOPK - 1] = key;
#pragma unroll
                for (int i = TOPK - 1; i > 0; --i) {
                    unsigned lo  = t[i - 1] < t[i] ? t[i - 1] : t[i];
                    unsigned hi2 = t[i - 1] < t[i] ? t[i]     : t[i - 1];
                    t[i - 1] = lo; t[i] = hi2;
                }
            }
        }
    }

    // 10-round tournament: global min of lane heads; winner pops (keys unique).
    unsigned mine = 0u, key0 = 0u;
#pragma unroll
    for (int r = 0; r < TOPK; ++r) {
        unsigned v = t[0];
#pragma unroll
        for (int off = 32; off >= 1; off >>= 1) {
            unsigned o = __shfl_xor(v, off, 64);
            v = o < v ? o : v;
        }
        if (t[0] == v) {                       // exactly one lane matches
#pragma unroll
            for (int i = 0; i < TOPK - 1; ++i) t[i] = t[i + 1];
            t[TOPK - 1] = 0xFFFFFFFFu;
        }
        if (lane == r) mine = v;
        if (r == 0) key0 = v;
    }
    if (lane < TOPK) nn_out[row * TOPK + lane] = (int)(mine & 0x3FFFu);
    if (lane == 0)   matched_out[row] = (key0 < (INF_D2 << 14)) ? 1 : 0;
}

// ---------------------------------------------------------------- MDN / occ / int
// One thread per (row, t): computes m*logp, m*int_term; t==0 thread does occ term.
__global__ __launch_bounds__(256) void mdn_kernel(
        const float* __restrict__ mu_off, const float* __restrict__ log_sig_off,
        const float* __restrict__ mu_int, const float* __restrict__ occ_logit,
        const float* __restrict__ mix_logit, const float* __restrict__ lidar_features,
        const int* __restrict__ radar_indices, const int* __restrict__ lidar_indices,
        const int* __restrict__ nn, const int* __restrict__ matched,
        float* __restrict__ logp_part, float* __restrict__ int_part,
        float* __restrict__ occ_part) {
    int gid = blockIdx.x * 256 + threadIdx.x;
    if (gid >= NRAD * TOPK) return;
    int n  = gid / TOPK;
    int tt = gid - n * TOPK;
    int m  = matched[n];
    float mf = (float)m;
    int nni = nn[gid];

    int4 ri = ((const int4*)radar_indices)[n];
    int4 li = ((const int4*)lidar_indices)[nni];
    // y = offs_zyx reversed -> (x,y,z); zeroed when unmatched
    float y0 = mf * (float)(li.w - ri.w);
    float y1 = mf * (float)(li.z - ri.z);
    float y2 = mf * (float)(li.y - ri.y);

    // log_softmax denominator over mixture logits
    float mix[KMIX];
    float mmax = -1e30f;
#pragma unroll
    for (int k = 0; k < KMIX; ++k) {
        mix[k] = mix_logit[n * KMIX + k];
        mmax = fmaxf(mmax, mix[k]);
    }
    float msum = 0.f;
#pragma unroll
    for (int k = 0; k < KMIX; ++k) msum += expf(mix[k] - mmax);
    float logZ = mmax + logf(msum);

    float lpost[KMIX];
    float pmax = -1e30f;
#pragma unroll
    for (int k = 0; k < KMIX; ++k) {
        int bidx = (n * KMIX + k) * 3;
        float mu0 = mu_off[bidx + 0], mu1 = mu_off[bidx + 1], mu2 = mu_off[bidx + 2];
        float l0 = log_sig_off[bidx + 0], l1 = log_sig_off[bidx + 1], l2 = log_sig_off[bidx + 2];
        float s0 = expf(2.f * l0) + 1e-12f;
        float s1 = expf(2.f * l1) + 1e-12f;
        float s2 = expf(2.f * l2) + 1e-12f;
        float d0 = y0 - mu0, d1 = y1 - mu1, d2v = y2 - mu2;
        float q = d0 * d0 / s0 + d1 * d1 / s1 + d2v * d2v / s2
                + 2.f * (l0 + l1 + l2) + 3.f * LOG2PI;
        lpost[k] = -0.5f * q + (mix[k] - logZ);
        pmax = fmaxf(pmax, lpost[k]);
    }
    float ex[KMIX];
    float se = 0.f;
#pragma unroll
    for (int k = 0; k < KMIX; ++k) { ex[k] = expf(lpost[k] - pmax); se += ex[k]; }
    float logp = pmax + logf(se);

    float gt = 0.f;
    if (m) {
        const float* lf = lidar_features + nni * CF;
        gt = 0.25f * (lf[3] + lf[7] + lf[11] + lf[15]);
    }
    float inv_se = 1.f / se;
    float isum = 0.f;
#pragma unroll
    for (int k = 0; k < KMIX; ++k)
        isum += ex[k] * inv_se * fabsf(mu_int[n * KMIX + k] - gt);

    logp_part[gid] = mf * logp;
    int_part[gid]  = mf * isum;

    if (tt == 0) {
        float oa = -1e30f;
#pragma unroll
        for (int k = 0; k < KMIX; ++k) oa = fmaxf(oa, occ_logit[n * KMIX + k]);
        float soft_abs = log1pf(expf(-fabsf(oa)));
        float sp_neg = soft_abs + fmaxf(-oa, 0.f);   // softplus(-oa)
        float sp_pos = soft_abs + fmaxf(oa, 0.f);    // softplus(oa)
        occ_part[n] = mf * sp_neg + (1.f - mf) * sp_pos;
    }
}

// ---------------------------------------------------------------- finalize
__device__ __forceinline__ float waveReduceSum(float v) {
#pragma unroll
    for (int off = 32; off >= 1; off >>= 1) v += __shfl_down(v, off, 64);
    return v;
}

__global__ __launch_bounds__(1024) void finalize_kernel(
        const float* __restrict__ logp_part, const float* __restrict__ int_part,
        const float* __restrict__ occ_part, const int* __restrict__ matched,
        float* __restrict__ out) {
    __shared__ float sA[16], sB[16], sC[16], sD[16];
    int tid = threadIdx.x;
    float a = 0.f, b = 0.f, c = 0.f, d = 0.f;
    for (int i = tid; i < NRAD * TOPK; i += 1024) { a += logp_part[i]; b += int_part[i]; }
    for (int i = tid; i < NRAD; i += 1024) { c += occ_part[i]; d += (float)matched[i]; }
    a = waveReduceSum(a); b = waveReduceSum(b);
    c = waveReduceSum(c); d = waveReduceSum(d);
    int wid = tid >> 6, lane = tid & 63;
    if (lane == 0) { sA[wid] = a; sB[wid] = b; sC[wid] = c; sD[wid] = d; }
    __syncthreads();
    if (wid == 0) {
        a = (lane < 16) ? sA[lane] : 0.f;
        b = (lane < 16) ? sB[lane] : 0.f;
        c = (lane < 16) ? sC[lane] : 0.f;
        d = (lane < 16) ? sD[lane] : 0.f;
        a = waveReduceSum(a); b = waveReduceSum(b);
        c = waveReduceSum(c); d = waveReduceSum(d);
        if (lane == 0) {
            float cnt = d;
            float occ_loss = c / (float)NRAD;
            float mdn_nll  = -a / (cnt * (float)TOPK);
            float int_loss = b / (cnt * (float)TOPK * (float)KMIX);
            out[0] = 0.2f * occ_loss + mdn_nll + 0.1f * int_loss;
        }
    }
}

// ---------------------------------------------------------------- launch
extern "C" void kernel_launch(void* const* d_in, const int* in_sizes, int n_in,
                              void* d_out, int out_size, void* d_ws, size_t ws_size,
                              hipStream_t stream) {
    const float* mu_off         = (const float*)d_in[0];
    const float* log_sig_off    = (const float*)d_in[1];
    const float* mu_int         = (const float*)d_in[2];
    const float* occ_logit      = (const float*)d_in[3];
    const float* mix_logit      = (const float*)d_in[4];
    const float* lidar_features = (const float*)d_in[5];
    const int*   radar_indices  = (const int*)d_in[6];
    const int*   lidar_indices  = (const int*)d_in[7];
    float* out = (float*)d_out;

    char* ws = (char*)d_ws;
    unsigned* packed   = (unsigned*)(ws + 0);        // 16384*4  = 64 KB
    int*      nn       = (int*)(ws + 65536);         // 40960*4  = 160 KB
    int*      matched  = (int*)(ws + 229376);        // 4096*4   = 16 KB
    float*    logp_prt = (float*)(ws + 245760);      // 40960*4  = 160 KB
    float*    int_prt  = (float*)(ws + 409600);      // 40960*4  = 160 KB
    float*    occ_prt  = (float*)(ws + 573440);      // 4096*4   = 16 KB

    hipLaunchKernelGGL(pack_lidar, dim3(NLID / 256), dim3(256), 0, stream,
                       lidar_indices, packed);
    hipLaunchKernelGGL(topk_kernel, dim3(NRAD / 4), dim3(256), 0, stream,
                       packed, radar_indices, nn, matched);
    hipLaunchKernelGGL(mdn_kernel, dim3((NRAD * TOPK + 255) / 256), dim3(256), 0, stream,
                       mu_off, log_sig_off, mu_int, occ_logit, mix_logit,
                       lidar_features, radar_indices, lidar_indices,
                       nn, matched, logp_prt, int_prt, occ_prt);
    hipLaunchKernelGGL(finalize_kernel, dim3(1), dim3(1024), 0, stream,
                       logp_prt, int_prt, occ_prt, matched, out);
}

// Round 2
// 126.308 us; speedup vs baseline: 1.3355x; 1.3355x over previous
//
#include <hip/hip_runtime.h>
#include <cstdint>

#define NRAD 4096
#define NLID 16384
#define KMIX 8
#define TOPK 10
#define CF   16
#define LOG2PI 1.8378770664093453f

static constexpr unsigned INF_D2 = 62851u;   // > max real d2 (40^2 + 2*175^2 = 62850)

// ---------------------------------------------------------------- helpers
__device__ __forceinline__ void insert_key(unsigned (&t)[TOPK], unsigned key) {
    // t ascending; branch-free exact insert of key into 10 smallest.
    // t[i] = min(max(key, t_old[i-1]), t_old[i]) descending, then t[0]=min.
#pragma unroll
    for (int i = TOPK - 1; i >= 1; --i) {
        unsigned hi = key > t[i - 1] ? key : t[i - 1];
        t[i] = hi < t[i] ? hi : t[i];
    }
    t[0] = key < t[0] ? key : t[0];
}

__device__ __forceinline__ void merge10(unsigned (&t)[TOPK], int lane,
                                        unsigned& mine, unsigned& first, unsigned& tenth) {
#pragma unroll
    for (int r = 0; r < TOPK; ++r) {
        unsigned v = t[0];
#pragma unroll
        for (int off = 32; off >= 1; off >>= 1) {
            unsigned o = __shfl_xor(v, off, 64);
            v = o < v ? o : v;
        }
        if (t[0] == v) {                       // unique keys -> exactly one popper
#pragma unroll
            for (int i = 0; i < TOPK - 1; ++i) t[i] = t[i + 1];
            t[TOPK - 1] = 0xFFFFFFFFu;
        }
        if (lane == r) mine = v;
        if (r == 0) first = v;
        if (r == TOPK - 1) tenth = v;
    }
}

__device__ __forceinline__ float waveReduceSum(float v) {
#pragma unroll
    for (int off = 32; off >= 1; off >>= 1) v += __shfl_down(v, off, 64);
    return v;
}

// ---------------------------------------------------------------- prep
// Single block: pack positions, histogram batches, batch-compact lidar,
// zero the loss accumulators. Scatter order nondeterministic == fine
// (top-k selection over keys is scan-order independent).
__global__ __launch_bounds__(1024) void prep_kernel(
        const int* __restrict__ lidar_indices,
        unsigned* __restrict__ packed_full,
        uint2* __restrict__ compacted,
        int* __restrict__ meta,        // cnt[4], base[4]
        float* __restrict__ accum) {   // [4] zeroed here
    __shared__ int hist[4];
    __shared__ int cursor[4];
    int tid = threadIdx.x;
    int lane = tid & 63;
    if (tid < 4) { hist[tid] = 0; accum[tid] = 0.f; }
    __syncthreads();

    int pb[16]; unsigned pp[16];
    int local[4] = {0, 0, 0, 0};
#pragma unroll
    for (int it = 0; it < 16; ++it) {
        int i = it * 1024 + tid;
        int4 li = ((const int4*)lidar_indices)[i];
        int b = li.x;
        unsigned pos = ((unsigned)li.y << 16) | ((unsigned)li.z << 8) | (unsigned)li.w;
        packed_full[i] = ((unsigned)b << 22) | pos;
        pb[it] = b; pp[it] = pos;
#pragma unroll
        for (int b2 = 0; b2 < 4; ++b2)
            local[b2] += (int)__popcll(__ballot(b == b2));
    }
    if (lane == 0) {
#pragma unroll
        for (int b2 = 0; b2 < 4; ++b2) atomicAdd(&hist[b2], local[b2]);
    }
    __syncthreads();
    if (tid == 0) {
        int b0 = 0;
#pragma unroll
        for (int b2 = 0; b2 < 4; ++b2) {
            meta[b2] = hist[b2];
            meta[4 + b2] = b0;
            cursor[b2] = b0;
            b0 = (b0 + hist[b2] + 1) & ~1;   // keep bases even (16B alignment)
        }
    }
    __syncthreads();
#pragma unroll
    for (int it = 0; it < 16; ++it) {
        int i = it * 1024 + tid;
        int b = pb[it];
#pragma unroll
        for (int b2 = 0; b2 < 4; ++b2) {
            unsigned long long mask = __ballot(b == b2);
            if (b == b2) {
                int leader = __ffsll((unsigned long long)mask) - 1;
                int off = (int)__popcll(mask & ((1ull << lane) - 1ull));
                int s = 0;
                if (lane == leader) s = atomicAdd(&cursor[b2], (int)__popcll(mask));
                s = __shfl(s, leader, 64);
                compacted[s + off] = make_uint2(pp[it], (unsigned)i);
            }
        }
    }
}

// ---------------------------------------------------------------- top-10 NN
// One wave per radar row; scans only same-batch compacted candidates.
// Key = (d2<<14)|idx; unsigned-min == lax.top_k(-d2) order incl. index tie-break.
__global__ __launch_bounds__(256) void topk_kernel(
        const uint2* __restrict__ compacted,
        const unsigned* __restrict__ packed_full,
        const int* __restrict__ meta,
        const int* __restrict__ radar_indices,
        int* __restrict__ nn_out, int* __restrict__ matched_out) {
    int lane = threadIdx.x & 63;
    int row  = blockIdx.x * 4 + (threadIdx.x >> 6);
    int4 ri = ((const int4*)radar_indices)[row];
    int rb = ri.x, rz = ri.y, ry = ri.z, rx = ri.w;
    int c_cnt  = meta[rb];
    int c_base = meta[4 + rb];

    unsigned t[TOPK];
#pragma unroll
    for (int i = 0; i < TOPK; ++i) t[i] = 0xFFFFFFFFu;

    const uint4* src = (const uint4*)(compacted + c_base);   // base even -> 16B aligned
    int iters = (c_cnt + 127) >> 7;
    for (int it = 0; it < iters; ++it) {
        uint4 q = src[it * 64 + lane];          // two candidates (pos,idx,pos,idx)
        int c0 = (it * 64 + lane) * 2;
        {
            int z = (int)((q.x >> 16) & 63u), y = (int)((q.x >> 8) & 255u), x = (int)(q.x & 255u);
            int dz = z - rz, dy = y - ry, dx = x - rx;
            unsigned d2 = (unsigned)(dz * dz + dy * dy + dx * dx);
            unsigned key = (c0 < c_cnt) ? ((d2 << 14) | q.y) : 0xFFFFFFFFu;
            insert_key(t, key);
        }
        {
            int z = (int)((q.z >> 16) & 63u), y = (int)((q.z >> 8) & 255u), x = (int)(q.z & 255u);
            int dz = z - rz, dy = y - ry, dx = x - rx;
            unsigned d2 = (unsigned)(dz * dz + dy * dy + dx * dx);
            unsigned key = (c0 + 1 < c_cnt) ? ((d2 << 14) | q.w) : 0xFFFFFFFFu;
            insert_key(t, key);
        }
    }

    unsigned mine = 0, first = 0, tenth = 0;
    merge10(t, lane, mine, first, tenth);
    bool matched = true;   // normal path: >=10 same-batch candidates exist

    if (tenth == 0xFFFFFFFFu) {
        // Degenerate row (<10 same-batch lidar): exact full scan w/ INF keys.
#pragma unroll
        for (int i = 0; i < TOPK; ++i) t[i] = 0xFFFFFFFFu;
        for (int it = 0; it < NLID / 256; ++it) {
            uint4 p4 = ((const uint4*)packed_full)[it * 64 + lane];
            unsigned base = it * 256 + lane * 4;
            unsigned ps[4] = {p4.x, p4.y, p4.z, p4.w};
#pragma unroll
            for (int j = 0; j < 4; ++j) {
                unsigned p = ps[j];
                int b  = (int)(p >> 22);
                int dz = (int)((p >> 16) & 63u)  - rz;
                int dy = (int)((p >> 8)  & 255u) - ry;
                int dx = (int)(p & 255u)         - rx;
                unsigned d2 = (unsigned)(dz * dz + dy * dy + dx * dx);
                unsigned hi = (b == rb) ? d2 : INF_D2;
                insert_key(t, (hi << 14) | (base + j));
            }
        }
        merge10(t, lane, mine, first, tenth);
        matched = first < (INF_D2 << 14);
    }

    if (lane < TOPK) nn_out[row * TOPK + lane] = (int)(mine & 0x3FFFu);
    if (lane == 0)   matched_out[row] = matched ? 1 : 0;
}

// ---------------------------------------------------------------- MDN / occ / int
__global__ __launch_bounds__(256) void mdn_kernel(
        const float* __restrict__ mu_off, const float* __restrict__ log_sig_off,
        const float* __restrict__ mu_int, const float* __restrict__ occ_logit,
        const float* __restrict__ mix_logit, const float* __restrict__ lidar_features,
        const int* __restrict__ radar_indices, const int* __restrict__ lidar_indices,
        const int* __restrict__ nn, const int* __restrict__ matched,
        float* __restrict__ accum) {   // {logp_sum, int_sum, occ_sum, match_cnt}
    int gid = blockIdx.x * 256 + threadIdx.x;
    int n  = gid / TOPK;
    int tt = gid - n * TOPK;
    int m  = matched[n];
    float mf = (float)m;
    int nni = nn[gid];

    int4 ri = ((const int4*)radar_indices)[n];
    int4 li = ((const int4*)lidar_indices)[nni];
    float y0 = mf * (float)(li.w - ri.w);
    float y1 = mf * (float)(li.z - ri.z);
    float y2 = mf * (float)(li.y - ri.y);

    float mix[KMIX];
    float mmax = -1e30f;
#pragma unroll
    for (int k = 0; k < KMIX; ++k) {
        mix[k] = mix_logit[n * KMIX + k];
        mmax = fmaxf(mmax, mix[k]);
    }
    float msum = 0.f;
#pragma unroll
    for (int k = 0; k < KMIX; ++k) msum += expf(mix[k] - mmax);
    float logZ = mmax + logf(msum);

    float lpost[KMIX];
    float pmax = -1e30f;
#pragma unroll
    for (int k = 0; k < KMIX; ++k) {
        int bidx = (n * KMIX + k) * 3;
        float mu0 = mu_off[bidx + 0], mu1 = mu_off[bidx + 1], mu2 = mu_off[bidx + 2];
        float l0 = log_sig_off[bidx + 0], l1 = log_sig_off[bidx + 1], l2 = log_sig_off[bidx + 2];
        float s0 = expf(2.f * l0) + 1e-12f;
        float s1 = expf(2.f * l1) + 1e-12f;
        float s2 = expf(2.f * l2) + 1e-12f;
        float d0 = y0 - mu0, d1 = y1 - mu1, d2v = y2 - mu2;
        float q = d0 * d0 / s0 + d1 * d1 / s1 + d2v * d2v / s2
                + 2.f * (l0 + l1 + l2) + 3.f * LOG2PI;
        lpost[k] = -0.5f * q + (mix[k] - logZ);
        pmax = fmaxf(pmax, lpost[k]);
    }
    float ex[KMIX];
    float se = 0.f;
#pragma unroll
    for (int k = 0; k < KMIX; ++k) { ex[k] = expf(lpost[k] - pmax); se += ex[k]; }
    float logp = pmax + logf(se);

    float gt = 0.f;
    if (m) {
        const float* lf = lidar_features + nni * CF;
        gt = 0.25f * (lf[3] + lf[7] + lf[11] + lf[15]);
    }
    float inv_se = 1.f / se;
    float isum = 0.f;
#pragma unroll
    for (int k = 0; k < KMIX; ++k)
        isum += ex[k] * inv_se * fabsf(mu_int[n * KMIX + k] - gt);

    float lp = mf * logp;
    float ip = mf * isum;
    float oc = 0.f, mc = 0.f;
    if (tt == 0) {
        float oa = -1e30f;
#pragma unroll
        for (int k = 0; k < KMIX; ++k) oa = fmaxf(oa, occ_logit[n * KMIX + k]);
        float soft_abs = log1pf(expf(-fabsf(oa)));
        float sp_neg = soft_abs + fmaxf(-oa, 0.f);
        float sp_pos = soft_abs + fmaxf(oa, 0.f);
        oc = mf * sp_neg + (1.f - mf) * sp_pos;
        mc = mf;
    }

    // block reduce 4 values -> 4 atomics per block
    lp = waveReduceSum(lp); ip = waveReduceSum(ip);
    oc = waveReduceSum(oc); mc = waveReduceSum(mc);
    __shared__ float sA[4], sB[4], sC[4], sD[4];
    int wid = threadIdx.x >> 6, lane = threadIdx.x & 63;
    if (lane == 0) { sA[wid] = lp; sB[wid] = ip; sC[wid] = oc; sD[wid] = mc; }
    __syncthreads();
    if (threadIdx.x == 0) {
        atomicAdd(&accum[0], sA[0] + sA[1] + sA[2] + sA[3]);
        atomicAdd(&accum[1], sB[0] + sB[1] + sB[2] + sB[3]);
        atomicAdd(&accum[2], sC[0] + sC[1] + sC[2] + sC[3]);
        atomicAdd(&accum[3], sD[0] + sD[1] + sD[2] + sD[3]);
    }
}

// ---------------------------------------------------------------- finalize
__global__ void final_kernel(const float* __restrict__ accum, float* __restrict__ out) {
    if (threadIdx.x == 0) {
        float cnt = accum[3];
        float occ_loss = accum[2] / (float)NRAD;
        float mdn_nll  = -accum[0] / (cnt * (float)TOPK);
        float int_loss = accum[1] / (cnt * (float)TOPK * (float)KMIX);
        out[0] = 0.2f * occ_loss + mdn_nll + 0.1f * int_loss;
    }
}

// ---------------------------------------------------------------- launch
extern "C" void kernel_launch(void* const* d_in, const int* in_sizes, int n_in,
                              void* d_out, int out_size, void* d_ws, size_t ws_size,
                              hipStream_t stream) {
    const float* mu_off         = (const float*)d_in[0];
    const float* log_sig_off    = (const float*)d_in[1];
    const float* mu_int         = (const float*)d_in[2];
    const float* occ_logit      = (const float*)d_in[3];
    const float* mix_logit      = (const float*)d_in[4];
    const float* lidar_features = (const float*)d_in[5];
    const int*   radar_indices  = (const int*)d_in[6];
    const int*   lidar_indices  = (const int*)d_in[7];
    float* out = (float*)d_out;

    char* ws = (char*)d_ws;
    unsigned* packed_full = (unsigned*)(ws + 0);        //  64 KB
    uint2*    compacted   = (uint2*)(ws + 65536);       // 16640*8 = 133120 B (pad incl.)
    int*      meta        = (int*)(ws + 204800);        //  32 B (cnt[4], base[4])
    float*    accum       = (float*)(ws + 204864);      //  16 B
    int*      nn          = (int*)(ws + 208896);        // 160 KB
    int*      matched     = (int*)(ws + 372736);        //  16 KB

    hipLaunchKernelGGL(prep_kernel, dim3(1), dim3(1024), 0, stream,
                       lidar_indices, packed_full, compacted, meta, accum);
    hipLaunchKernelGGL(topk_kernel, dim3(NRAD / 4), dim3(256), 0, stream,
                       compacted, packed_full, meta, radar_indices, nn, matched);
    hipLaunchKernelGGL(mdn_kernel, dim3(NRAD * TOPK / 256), dim3(256), 0, stream,
                       mu_off, log_sig_off, mu_int, occ_logit, mix_logit,
                       lidar_features, radar_indices, lidar_indices,
                       nn, matched, accum);
    hipLaunchKernelGGL(final_kernel, dim3(1), dim3(64), 0, stream, accum, out);
}

// Round 3
// 121.800 us; speedup vs baseline: 1.3850x; 1.0370x over previous
//
#include <hip/hip_runtime.h>
#include <cstdint>

#define NRAD 4096
#define NLID 16384
#define KMIX 8
#define TOPK 10
#define CF   16
#define LOG2PI 1.8378770664093453f

static constexpr unsigned INF_D2 = 62851u;   // > max real d2 (40^2 + 2*175^2 = 62850)

// ---------------------------------------------------------------- helpers
__device__ __forceinline__ void insert_key(unsigned (&t)[TOPK], unsigned key) {
    // t ascending; branch-free exact insert of key into 10 smallest.
#pragma unroll
    for (int i = TOPK - 1; i >= 1; --i) {
        unsigned hi = key > t[i - 1] ? key : t[i - 1];
        t[i] = hi < t[i] ? hi : t[i];
    }
    t[0] = key < t[0] ? key : t[0];
}

__device__ __forceinline__ void merge10(unsigned (&t)[TOPK], int lane,
                                        unsigned& mine, unsigned& first, unsigned& tenth) {
#pragma unroll
    for (int r = 0; r < TOPK; ++r) {
        unsigned v = t[0];
#pragma unroll
        for (int off = 32; off >= 1; off >>= 1) {
            unsigned o = __shfl_xor(v, off, 64);
            v = o < v ? o : v;
        }
        if (t[0] == v) {                       // unique keys -> exactly one popper
#pragma unroll
            for (int i = 0; i < TOPK - 1; ++i) t[i] = t[i + 1];
            t[TOPK - 1] = 0xFFFFFFFFu;
        }
        if (lane == r) mine = v;
        if (r == 0) first = v;
        if (r == TOPK - 1) tenth = v;
    }
}

__device__ __forceinline__ float waveReduceSum(float v) {
#pragma unroll
    for (int off = 32; off >= 1; off >>= 1) v += __shfl_down(v, off, 64);
    return v;
}

// ---------------------------------------------------------------- prep (multi-block)
// Pack positions; scatter each lidar into its batch's fixed region
// (16384 entries per batch) via global atomic cursor. cursor[b] ends == count.
// Scatter order nondeterministic == fine (top-k over keys is order-independent).
__global__ __launch_bounds__(256) void prep_kernel(
        const int* __restrict__ lidar_indices,
        unsigned* __restrict__ packed_full,
        uint2* __restrict__ compacted,
        int* __restrict__ cursor) {           // [4], pre-zeroed
    int i = blockIdx.x * 256 + threadIdx.x;
    int lane = threadIdx.x & 63;
    int4 li = ((const int4*)lidar_indices)[i];
    int b = li.x;
    unsigned pos = ((unsigned)li.y << 16) | ((unsigned)li.z << 8) | (unsigned)li.w;
    packed_full[i] = ((unsigned)b << 22) | pos;
#pragma unroll
    for (int b2 = 0; b2 < 4; ++b2) {
        unsigned long long mask = __ballot(b == b2);
        if (b == b2) {
            int leader = __ffsll(mask) - 1;
            int off = (int)__popcll(mask & ((1ull << lane) - 1ull));
            int s = 0;
            if (lane == leader) s = atomicAdd(&cursor[b2], (int)__popcll(mask));
            s = __shfl(s, leader, 64);
            compacted[b2 * NLID + s + off] = make_uint2(pos, (unsigned)i);
        }
    }
}

// ---------------------------------------------------------------- top-10 NN
// One wave per radar row; scans only same-batch compacted candidates.
// Key = (d2<<14)|idx; unsigned-min == lax.top_k(-d2) order incl. index tie-break.
__global__ __launch_bounds__(256) void topk_kernel(
        const uint2* __restrict__ compacted,
        const unsigned* __restrict__ packed_full,
        const int* __restrict__ cursor,
        const int* __restrict__ radar_indices,
        int* __restrict__ nn_out, int* __restrict__ matched_out) {
    int lane = threadIdx.x & 63;
    int row  = blockIdx.x * 4 + (threadIdx.x >> 6);
    int4 ri = ((const int4*)radar_indices)[row];
    int rb = ri.x, rz = ri.y, ry = ri.z, rx = ri.w;
    int c_cnt = cursor[rb];

    unsigned t[TOPK];
#pragma unroll
    for (int i = 0; i < TOPK; ++i) t[i] = 0xFFFFFFFFu;

    const uint4* src = (const uint4*)(compacted + rb * NLID);  // 16B aligned
    int iters = (c_cnt + 127) >> 7;
    uint4 q = src[lane];
    for (int it = 0; it < iters; ++it) {
        uint4 qn = q;
        if (it + 1 < iters) qn = src[(it + 1) * 64 + lane];    // prefetch next
        int c0 = (it * 64 + lane) * 2;
        {
            int dz = (int)((q.x >> 16) & 63u)  - rz;
            int dy = (int)((q.x >> 8)  & 255u) - ry;
            int dx = (int)(q.x & 255u)         - rx;
            unsigned d2 = (unsigned)(dz * dz + dy * dy + dx * dx);
            unsigned key = (c0 < c_cnt) ? ((d2 << 14) | q.y) : 0xFFFFFFFFu;
            if (key < t[TOPK - 1]) insert_key(t, key);
        }
        {
            int dz = (int)((q.z >> 16) & 63u)  - rz;
            int dy = (int)((q.z >> 8)  & 255u) - ry;
            int dx = (int)(q.z & 255u)         - rx;
            unsigned d2 = (unsigned)(dz * dz + dy * dy + dx * dx);
            unsigned key = (c0 + 1 < c_cnt) ? ((d2 << 14) | q.w) : 0xFFFFFFFFu;
            if (key < t[TOPK - 1]) insert_key(t, key);
        }
        q = qn;
    }

    unsigned mine = 0, first = 0, tenth = 0;
    merge10(t, lane, mine, first, tenth);
    bool matched = true;   // normal path: >=10 same-batch candidates exist

    if (tenth == 0xFFFFFFFFu) {
        // Degenerate row (<10 same-batch lidar): exact full scan w/ INF keys.
#pragma unroll
        for (int i = 0; i < TOPK; ++i) t[i] = 0xFFFFFFFFu;
        for (int it = 0; it < NLID / 256; ++it) {
            uint4 p4 = ((const uint4*)packed_full)[it * 64 + lane];
            unsigned base = it * 256 + lane * 4;
            unsigned ps[4] = {p4.x, p4.y, p4.z, p4.w};
#pragma unroll
            for (int j = 0; j < 4; ++j) {
                unsigned p = ps[j];
                int b  = (int)(p >> 22);
                int dz = (int)((p >> 16) & 63u)  - rz;
                int dy = (int)((p >> 8)  & 255u) - ry;
                int dx = (int)(p & 255u)         - rx;
                unsigned d2 = (unsigned)(dz * dz + dy * dy + dx * dx);
                unsigned hi = (b == rb) ? d2 : INF_D2;
                insert_key(t, (hi << 14) | (base + j));
            }
        }
        merge10(t, lane, mine, first, tenth);
        matched = first < (INF_D2 << 14);
    }

    if (lane < TOPK) nn_out[row * TOPK + lane] = (int)(mine & 0x3FFFu);
    if (lane == 0)   matched_out[row] = matched ? 1 : 0;
}

// ---------------------------------------------------------------- MDN / occ / int (+fused finalize)
__global__ __launch_bounds__(256) void mdn_kernel(
        const float* __restrict__ mu_off, const float* __restrict__ log_sig_off,
        const float* __restrict__ mu_int, const float* __restrict__ occ_logit,
        const float* __restrict__ mix_logit, const float* __restrict__ lidar_features,
        const int* __restrict__ radar_indices, const int* __restrict__ lidar_indices,
        const int* __restrict__ nn, const int* __restrict__ matched,
        float* __restrict__ accum,            // {logp,int,occ,cnt}, pre-zeroed
        unsigned* __restrict__ dctr,          // pre-zeroed
        float* __restrict__ out) {
    int gid = blockIdx.x * 256 + threadIdx.x;
    int n  = gid / TOPK;
    int tt = gid - n * TOPK;
    int m  = matched[n];
    float mf = (float)m;
    int nni = nn[gid];

    int4 ri = ((const int4*)radar_indices)[n];
    int4 li = ((const int4*)lidar_indices)[nni];
    float y0 = mf * (float)(li.w - ri.w);
    float y1 = mf * (float)(li.z - ri.z);
    float y2 = mf * (float)(li.y - ri.y);

    float mix[KMIX];
    float mmax = -1e30f;
#pragma unroll
    for (int k = 0; k < KMIX; ++k) {
        mix[k] = mix_logit[n * KMIX + k];
        mmax = fmaxf(mmax, mix[k]);
    }
    float msum = 0.f;
#pragma unroll
    for (int k = 0; k < KMIX; ++k) msum += expf(mix[k] - mmax);
    float logZ = mmax + logf(msum);

    float lpost[KMIX];
    float pmax = -1e30f;
#pragma unroll
    for (int k = 0; k < KMIX; ++k) {
        int bidx = (n * KMIX + k) * 3;
        float mu0 = mu_off[bidx + 0], mu1 = mu_off[bidx + 1], mu2 = mu_off[bidx + 2];
        float l0 = log_sig_off[bidx + 0], l1 = log_sig_off[bidx + 1], l2 = log_sig_off[bidx + 2];
        float s0 = expf(2.f * l0) + 1e-12f;
        float s1 = expf(2.f * l1) + 1e-12f;
        float s2 = expf(2.f * l2) + 1e-12f;
        float d0 = y0 - mu0, d1 = y1 - mu1, d2v = y2 - mu2;
        float q = d0 * d0 / s0 + d1 * d1 / s1 + d2v * d2v / s2
                + 2.f * (l0 + l1 + l2) + 3.f * LOG2PI;
        lpost[k] = -0.5f * q + (mix[k] - logZ);
        pmax = fmaxf(pmax, lpost[k]);
    }
    float ex[KMIX];
    float se = 0.f;
#pragma unroll
    for (int k = 0; k < KMIX; ++k) { ex[k] = expf(lpost[k] - pmax); se += ex[k]; }
    float logp = pmax + logf(se);

    float gt = 0.f;
    if (m) {
        const float* lf = lidar_features + nni * CF;
        gt = 0.25f * (lf[3] + lf[7] + lf[11] + lf[15]);
    }
    float inv_se = 1.f / se;
    float isum = 0.f;
#pragma unroll
    for (int k = 0; k < KMIX; ++k)
        isum += ex[k] * inv_se * fabsf(mu_int[n * KMIX + k] - gt);

    float lp = mf * logp;
    float ip = mf * isum;
    float oc = 0.f, mc = 0.f;
    if (tt == 0) {
        float oa = -1e30f;
#pragma unroll
        for (int k = 0; k < KMIX; ++k) oa = fmaxf(oa, occ_logit[n * KMIX + k]);
        float soft_abs = log1pf(expf(-fabsf(oa)));
        oc = mf * (soft_abs + fmaxf(-oa, 0.f)) + (1.f - mf) * (soft_abs + fmaxf(oa, 0.f));
        mc = mf;
    }

    lp = waveReduceSum(lp); ip = waveReduceSum(ip);
    oc = waveReduceSum(oc); mc = waveReduceSum(mc);
    __shared__ float sA[4], sB[4], sC[4], sD[4];
    int wid = threadIdx.x >> 6, lane = threadIdx.x & 63;
    if (lane == 0) { sA[wid] = lp; sB[wid] = ip; sC[wid] = oc; sD[wid] = mc; }
    __syncthreads();
    if (threadIdx.x == 0) {
        atomicAdd(&accum[0], sA[0] + sA[1] + sA[2] + sA[3]);
        atomicAdd(&accum[1], sB[0] + sB[1] + sB[2] + sB[3]);
        atomicAdd(&accum[2], sC[0] + sC[1] + sC[2] + sC[3]);
        atomicAdd(&accum[3], sD[0] + sD[1] + sD[2] + sD[3]);
        __threadfence();
        unsigned done = atomicAdd(dctr, 1u);
        if (done == gridDim.x - 1) {          // last block finalizes
            __threadfence();
            float a = __hip_atomic_load(&accum[0], __ATOMIC_RELAXED, __HIP_MEMORY_SCOPE_AGENT);
            float b = __hip_atomic_load(&accum[1], __ATOMIC_RELAXED, __HIP_MEMORY_SCOPE_AGENT);
            float c = __hip_atomic_load(&accum[2], __ATOMIC_RELAXED, __HIP_MEMORY_SCOPE_AGENT);
            float d = __hip_atomic_load(&accum[3], __ATOMIC_RELAXED, __HIP_MEMORY_SCOPE_AGENT);
            float occ_loss = c / (float)NRAD;
            float mdn_nll  = -a / (d * (float)TOPK);
            float int_loss = b / (d * (float)TOPK * (float)KMIX);
            out[0] = 0.2f * occ_loss + mdn_nll + 0.1f * int_loss;
        }
    }
}

// ---------------------------------------------------------------- launch
extern "C" void kernel_launch(void* const* d_in, const int* in_sizes, int n_in,
                              void* d_out, int out_size, void* d_ws, size_t ws_size,
                              hipStream_t stream) {
    const float* mu_off         = (const float*)d_in[0];
    const float* log_sig_off    = (const float*)d_in[1];
    const float* mu_int         = (const float*)d_in[2];
    const float* occ_logit      = (const float*)d_in[3];
    const float* mix_logit      = (const float*)d_in[4];
    const float* lidar_features = (const float*)d_in[5];
    const int*   radar_indices  = (const int*)d_in[6];
    const int*   lidar_indices  = (const int*)d_in[7];
    float* out = (float*)d_out;

    char* ws = (char*)d_ws;
    unsigned* packed_full = (unsigned*)(ws + 0);         //  64 KB
    uint2*    compacted   = (uint2*)(ws + 65536);        //  4*16384*8 = 512 KB
    int*      cursor      = (int*)(ws + 589824);         //  16 B
    float*    accum       = (float*)(ws + 589840);       //  16 B
    unsigned* dctr        = (unsigned*)(ws + 589856);    //  4 B
    int*      nn          = (int*)(ws + 589888);         //  160 KB
    int*      matched     = (int*)(ws + 753728);         //  16 KB

    hipMemsetAsync(ws + 589824, 0, 64, stream);          // cursors + accum + dctr

    hipLaunchKernelGGL(prep_kernel, dim3(NLID / 256), dim3(256), 0, stream,
                       lidar_indices, packed_full, compacted, cursor);
    hipLaunchKernelGGL(topk_kernel, dim3(NRAD / 4), dim3(256), 0, stream,
                       compacted, packed_full, cursor, radar_indices, nn, matched);
    hipLaunchKernelGGL(mdn_kernel, dim3(NRAD * TOPK / 256), dim3(256), 0, stream,
                       mu_off, log_sig_off, mu_int, occ_logit, mix_logit,
                       lidar_features, radar_indices, lidar_indices,
                       nn, matched, accum, dctr, out);
}